// Round 3
// baseline (650.615 us; speedup 1.0000x reference)
//
#include <hip/hip_runtime.h>
#include <stdint.h>

#define LMAXC 6
#define NSHC 49      // (LMAX+1)^2
#define CC 128
#define HH 256
#define NTOK 4096
#define NBA 182      // RB*RA = 14*13
#define EPSF 1e-5f
#define HTP 56       // h_t pitch in m (zero-padded 49->56, 112B rows, 16B aligned)

typedef __attribute__((ext_vector_type(8))) short bf16x8;
typedef __attribute__((ext_vector_type(4))) short s16x4;
typedef __attribute__((ext_vector_type(4))) float f32x4;

union U16x8 { uint4 v; ushort s[8]; };

__device__ __forceinline__ float bf2f(ushort u) {
  union { uint32_t i; float f; } w; w.i = ((uint32_t)u) << 16; return w.f;
}
__device__ __forceinline__ ushort f2bf(float f) {
  union { float f; uint32_t i; } w; w.f = f;
  uint32_t u = w.i;
  return (ushort)((u + 0x7fffu + ((u >> 16) & 1u)) >> 16);
}
__device__ __forceinline__ bf16x8 pack8(float4 a, float4 b) {
  bf16x8 r;
  r[0] = (short)f2bf(a.x); r[1] = (short)f2bf(a.y);
  r[2] = (short)f2bf(a.z); r[3] = (short)f2bf(a.w);
  r[4] = (short)f2bf(b.x); r[5] = (short)f2bf(b.y);
  r[6] = (short)f2bf(b.z); r[7] = (short)f2bf(b.w);
  return r;
}
__device__ __forceinline__ float siluf(float v) { return v / (1.f + __expf(-v)); }

__device__ __forceinline__ float block_sum(float v, volatile float* red, int t) {
  #pragma unroll
  for (int off = 32; off > 0; off >>= 1) v += __shfl_down(v, off, 64);
  __syncthreads();
  if ((t & 63) == 0) red[t >> 6] = v;
  __syncthreads();
  return red[0] + red[1] + red[2] + red[3];
}

// ---------------- K1: normalization  x (f32) -> xn (bf16); also zero h_t m-pad
__global__ __launch_bounds__(256) void k1_norm(
    const float* __restrict__ x, const float* __restrict__ ln0w,
    const float* __restrict__ ln0b, const float* __restrict__ affw,
    ushort* __restrict__ xn, ushort* __restrict__ h_t)
{
  __shared__ float red[4];
  int n = blockIdx.x, t = threadIdx.x;
  // zero h_t[n][o=t][49..56)
  {
    ushort* hp = h_t + (size_t)n * HH * HTP + (size_t)t * HTP;
    #pragma unroll
    for (int j = NSHC; j < HTP; ++j) hp[j] = 0;
  }
  const float4* xv = (const float4*)(x + (size_t)n * NSHC * CC);
  ushort* xnp = xn + (size_t)n * NSHC * CC;
  float4 vals[7];
  float s0 = 0.f, s0q = 0.f, fq = 0.f;
  #pragma unroll
  for (int p = 0; p < 7; ++p) {
    int idx = p * 256 + t;
    if (idx < 1568) {
      float4 v = xv[idx];
      vals[p] = v;
      int m = idx >> 5;
      if (m == 0) {
        s0  += v.x + v.y + v.z + v.w;
        s0q += v.x*v.x + v.y*v.y + v.z*v.z + v.w*v.w;
      } else {
        int l = (int)sqrtf((float)m + 0.5f);
        float bw = 1.f / ((float)(2*l+1) * 6.f);
        fq += bw * (v.x*v.x + v.y*v.y + v.z*v.z + v.w*v.w);
      }
    }
  }
  float S0 = block_sum(s0, red, t);
  float S0Q = block_sum(s0q, red, t);
  float FQ = block_sum(fq, red, t);
  float mu = S0 * (1.f / 128.f);
  float var = S0Q * (1.f / 128.f) - mu * mu;
  float rstd = rsqrtf(var + EPSF);
  float inv = rsqrtf(FQ * (1.f / 128.f) + EPSF);
  #pragma unroll
  for (int p = 0; p < 7; ++p) {
    int idx = p * 256 + t;
    if (idx < 1568) {
      int m = idx >> 5, c0 = (idx & 31) * 4;
      float4 v = vals[p];
      float o[4];
      if (m == 0) {
        o[0] = (v.x - mu) * rstd * ln0w[c0+0] + ln0b[c0+0];
        o[1] = (v.y - mu) * rstd * ln0w[c0+1] + ln0b[c0+1];
        o[2] = (v.z - mu) * rstd * ln0w[c0+2] + ln0b[c0+2];
        o[3] = (v.w - mu) * rstd * ln0w[c0+3] + ln0b[c0+3];
      } else {
        int l = (int)sqrtf((float)m + 0.5f);
        const float* aw = affw + (size_t)(l - 1) * CC;
        o[0] = v.x * inv * aw[c0+0];
        o[1] = v.y * inv * aw[c0+1];
        o[2] = v.z * inv * aw[c0+2];
        o[3] = v.w * inv * aw[c0+3];
      }
      s16x4 pk;
      #pragma unroll
      for (int j = 0; j < 4; ++j) pk[j] = (short)f2bf(o[j]);
      *(s16x4*)&xnp[idx * 4] = pk;
    }
  }
}

// ---------------- K2: grouped GEMM  h_t = (xn @ W1_l^T +b1) transposed, gate -> h2 row0
// grid (1600, 2): bx = chunk*50 + r; chunk = 128-token range (L2 locality for h_t sectors)
__global__ __launch_bounds__(256) void k2_h(
    const ushort* __restrict__ xn, const float* __restrict__ w1,
    const float* __restrict__ b1, const float* __restrict__ gate_w,
    const float* __restrict__ gate_b, ushort* __restrict__ h_t,
    ushort* __restrict__ h2)
{
  extern __shared__ char smem[];
  ushort* sA = (ushort*)smem;              // 128 x 72
  ushort* sB = sA + 128 * 72;              // 128 x 72
  int* offs_tbl = (int*)(sB + 128 * 72);   // 128, packed n*64+m
  const int off[9] = {0, 1, 4, 9, 16, 25, 36, 49, 50};
  int bx = blockIdx.x, colbase = blockIdx.y * 128, t = threadIdx.x;
  int c = bx / 50, r = bx - c * 50;
  int g = 0;
  #pragma unroll
  for (int k = 1; k < 8; ++k) if (r >= off[k]) g = k;
  int s = r - off[g];
  bool isGate = (g == 7);
  int l = isGate ? 0 : g;
  int d = isGate ? 1 : (2 * l + 1);
  int mbase = isGate ? 0 : l * l;
  const float* wB = isGate ? gate_w : (w1 + (size_t)l * HH * CC);
  int nb = c * d + s;                      // 128-row block within group

  if (t < 128) {
    int rr = nb * 128 + t;
    int nn = rr / d;
    int mm = mbase + (rr - nn * d);
    offs_tbl[t] = nn * 64 + mm;
  }
  __syncthreads();

  int wave = t >> 6, lane = t & 63, quad = lane >> 4, lan = lane & 15;
  int row0 = (wave >> 1) * 64, col0 = (wave & 1) * 64;
  f32x4 acc[4][4];
  f32x4 zf = {0.f, 0.f, 0.f, 0.f};
  #pragma unroll
  for (int a = 0; a < 4; ++a)
    #pragma unroll
    for (int b = 0; b < 4; ++b) acc[a][b] = zf;

  const uint4* xv = (const uint4*)xn;
  const float4* wv = (const float4*)wB;
  for (int kc = 0; kc < 2; ++kc) {         // K = 128 in 2 chunks of 64
    #pragma unroll
    for (int p = 0; p < 4; ++p) {
      int idx = p * 256 + t, row = idx >> 3, c8 = idx & 7;
      int of = offs_tbl[row];
      size_t xrow = (size_t)(of >> 6) * NSHC + (of & 63);
      *(uint4*)&sA[row * 72 + c8 * 8] = xv[xrow * 16 + kc * 8 + c8];
    }
    #pragma unroll
    for (int p = 0; p < 4; ++p) {
      int idx = p * 256 + t, row = idx >> 3, c8 = idx & 7;
      size_t base = (size_t)(colbase + row) * 32 + kc * 16 + c8 * 2;
      *(bf16x8*)&sB[row * 72 + c8 * 8] = pack8(wv[base], wv[base + 1]);
    }
    __syncthreads();
    #pragma unroll
    for (int ks = 0; ks < 2; ++ks) {
      bf16x8 av[4], bv[4];
      #pragma unroll
      for (int mt = 0; mt < 4; ++mt)
        av[mt] = *(const bf16x8*)&sA[(row0 + mt*16 + lan) * 72 + ks*32 + quad*8];
      #pragma unroll
      for (int nt = 0; nt < 4; ++nt)
        bv[nt] = *(const bf16x8*)&sB[(col0 + nt*16 + lan) * 72 + ks*32 + quad*8];
      #pragma unroll
      for (int mt = 0; mt < 4; ++mt)
        #pragma unroll
        for (int nt = 0; nt < 4; ++nt)
          acc[mt][nt] = __builtin_amdgcn_mfma_f32_16x16x32_bf16(av[mt], bv[nt], acc[mt][nt], 0, 0, 0);
    }
    __syncthreads();
  }

  #pragma unroll
  for (int nt = 0; nt < 4; ++nt) {
    int o = colbase + col0 + nt * 16 + lan;
    float bias = 0.f;
    if (g == 0) bias = b1[o];
    if (isGate) bias = gate_b[o];
    #pragma unroll
    for (int mt = 0; mt < 4; ++mt) {
      int rb = row0 + mt * 16 + quad * 4;
      #pragma unroll
      for (int i = 0; i < 4; ++i) {
        float v = acc[mt][nt][i] + bias;
        int of = offs_tbl[rb + i];
        if (isGate) {
          h2[(size_t)(of >> 6) * (NSHC * HH) + o] = f2bf(siluf(v));
        } else {
          h_t[((size_t)(of >> 6) * HH + o) * HTP + (of & 63)] = f2bf(v);
        }
      }
    }
  }
}

// ---------------- K3: grid transform  ht = FG^T @ silu(TG @ h) -> h2 rows 1..48
// 4 tokens/block; TG/FG^T fragments in registers; GEMM1 B-frags direct from global h_t
__global__ __launch_bounds__(256, 3) void k3_grid(
    const ushort* __restrict__ h_t, const float* __restrict__ tg,
    const float* __restrict__ fg, ushort* __restrict__ h2)
{
  __shared__ ushort sbuf[192 * 72];  // 27.6 KB: staging, then sG [o_loc][ba] pitch 200 (64x200=12800)
  int t = threadIdx.x;
  int wave = t >> 6, lane = t & 63, quad = lane >> 4, lan = lane & 15;

  bf16x8 a1[3][2];                   // TG fragments: rows wave*48.., K=64 (2 ksteps)
  {
    for (int i = t; i < 192 * 72; i += 256) sbuf[i] = 0;
    __syncthreads();
    for (int i = t; i < NBA * NSHC; i += 256) {
      int ba = i / NSHC, m = i - ba * NSHC;
      sbuf[ba * 72 + m] = f2bf(tg[i]);
    }
    __syncthreads();
    #pragma unroll
    for (int mt = 0; mt < 3; ++mt)
      #pragma unroll
      for (int ks = 0; ks < 2; ++ks)
        a1[mt][ks] = *(const bf16x8*)&sbuf[(wave*48 + mt*16 + lan) * 72 + ks*32 + quad*8];
    __syncthreads();
  }
  bf16x8 a2[6];                      // FG^T fragments: rows wave*16.., K=192 (6 ksteps)
  {
    for (int i = t; i < 64 * 200; i += 256) sbuf[i] = 0;
    __syncthreads();
    for (int i = t; i < NBA * NSHC; i += 256) {
      int ba = i / NSHC, m = i - ba * NSHC;
      sbuf[m * 200 + ba] = f2bf(fg[i]);
    }
    __syncthreads();
    #pragma unroll
    for (int ks = 0; ks < 6; ++ks)
      a2[ks] = *(const bf16x8*)&sbuf[(wave*16 + lan) * 200 + ks*32 + quad*8];
    __syncthreads();
  }
  ushort* sG = sbuf;                 // [o_loc][ba] pitch 200

  f32x4 zf = {0.f, 0.f, 0.f, 0.f};
  bf16x8 zb;
  #pragma unroll
  for (int j = 0; j < 8; ++j) zb[j] = 0;

  for (int it = 0; it < 4; ++it) {
    int tok = blockIdx.x * 4 + it;
    const ushort* hp = h_t + (size_t)tok * HH * HTP;

    for (int oc = 0; oc < 4; ++oc) {                   // H=256 in 4 chunks of 64
      // ---- GEMM1: P = TG @ h_t[tok][:, oc-chunk], B-frags from global ----
      f32x4 acc1[3][4];
      #pragma unroll
      for (int a = 0; a < 3; ++a)
        #pragma unroll
        for (int b = 0; b < 4; ++b) acc1[a][b] = zf;
      #pragma unroll
      for (int ks = 0; ks < 2; ++ks) {
        int kq = ks*32 + quad*8;
        bf16x8 bv[4];
        #pragma unroll
        for (int nt = 0; nt < 4; ++nt) {
          int col = oc*64 + nt*16 + lan;
          bv[nt] = (kq < HTP) ? *(const bf16x8*)(hp + (size_t)col * HTP + kq) : zb;
        }
        #pragma unroll
        for (int mt = 0; mt < 3; ++mt)
          #pragma unroll
          for (int nt = 0; nt < 4; ++nt)
            acc1[mt][nt] = __builtin_amdgcn_mfma_f32_16x16x32_bf16(a1[mt][ks], bv[nt], acc1[mt][nt], 0, 0, 0);
      }
      // ---- silu -> sG[o_loc][ba] ----
      #pragma unroll
      for (int mt = 0; mt < 3; ++mt) {
        int ba0 = wave*48 + mt*16 + quad*4;
        #pragma unroll
        for (int nt = 0; nt < 4; ++nt) {
          int o_loc = nt*16 + lan;
          s16x4 pk;
          #pragma unroll
          for (int i = 0; i < 4; ++i) pk[i] = (short)f2bf(siluf(acc1[mt][nt][i]));
          *(s16x4*)&sG[o_loc * 200 + ba0] = pk;
        }
      }
      __syncthreads();
      // ---- GEMM2: ht = FG^T @ P ----
      f32x4 acc2[4];
      #pragma unroll
      for (int b = 0; b < 4; ++b) acc2[b] = zf;
      #pragma unroll
      for (int ks = 0; ks < 6; ++ks) {
        #pragma unroll
        for (int nt = 0; nt < 4; ++nt) {
          bf16x8 bv = *(const bf16x8*)&sG[(nt*16 + lan) * 200 + ks*32 + quad*8];
          acc2[nt] = __builtin_amdgcn_mfma_f32_16x16x32_bf16(a2[ks], bv, acc2[nt], 0, 0, 0);
        }
      }
      int mrow = wave * 16 + quad * 4;
      #pragma unroll
      for (int nt = 0; nt < 4; ++nt) {
        int o = oc * 64 + nt * 16 + lan;
        #pragma unroll
        for (int i = 0; i < 4; ++i) {
          int m = mrow + i;
          if (m >= 1 && m < NSHC)
            h2[((size_t)tok * NSHC + m) * HH + o] = f2bf(acc2[nt][i]);
        }
      }
      __syncthreads();
    }
  }
}

// ---------------- K4: grouped GEMM  out = h2 @ W2_l^T (+b2 on m=0), f32 out --
// NOTE: h2 aliases d_out (each block reads exactly the rows it overwrites; all
// reads complete before epilogue stores).
__global__ __launch_bounds__(256) void k4_out(
    const ushort* __restrict__ h2, const float* __restrict__ w2,
    const float* __restrict__ b2, float* __restrict__ out)
{
  extern __shared__ char smem[];
  ushort* sA = (ushort*)smem;              // 128 x 72
  ushort* sB = sA + 128 * 72;              // 128 x 72
  int* offs_tbl = (int*)(sB + 128 * 72);
  const int cum[8] = {0, 32, 128, 288, 512, 800, 1152, 1568};
  int bx = blockIdx.x, t = threadIdx.x;
  int g = 0;
  #pragma unroll
  for (int k = 1; k < 7; ++k) if (bx >= cum[k]) g = k;
  int nb = bx - cum[g];
  int l = g, d = 2*l+1, mbase = l*l;
  if (t < 128) {
    int r = nb * 128 + t;
    int nn = r / d;
    offs_tbl[t] = nn * NSHC + mbase + (r - nn * d);
  }
  __syncthreads();
  int wave = t >> 6, lane = t & 63, quad = lane >> 4, lan = lane & 15;
  int row0 = (wave >> 1) * 64, col0 = (wave & 1) * 64;
  f32x4 acc[4][4];
  f32x4 zf = {0.f, 0.f, 0.f, 0.f};
  #pragma unroll
  for (int a = 0; a < 4; ++a)
    #pragma unroll
    for (int b = 0; b < 4; ++b) acc[a][b] = zf;

  const uint4* av4 = (const uint4*)h2;
  const float4* wv = (const float4*)(w2 + (size_t)l * CC * HH);
  for (int kc = 0; kc < 4; ++kc) {         // K = 256 in 4 chunks of 64
    #pragma unroll
    for (int p = 0; p < 4; ++p) {
      int idx = p * 256 + t, row = idx >> 3, c8 = idx & 7;
      *(uint4*)&sA[row * 72 + c8 * 8] = av4[(size_t)offs_tbl[row] * 32 + kc * 8 + c8];
    }
    #pragma unroll
    for (int p = 0; p < 4; ++p) {
      int idx = p * 256 + t, row = idx >> 3, c8 = idx & 7;
      size_t base = (size_t)row * 64 + kc * 16 + c8 * 2;
      *(bf16x8*)&sB[row * 72 + c8 * 8] = pack8(wv[base], wv[base + 1]);
    }
    __syncthreads();
    #pragma unroll
    for (int ks = 0; ks < 2; ++ks) {
      bf16x8 avf[4], bvf[4];
      #pragma unroll
      for (int mt = 0; mt < 4; ++mt)
        avf[mt] = *(const bf16x8*)&sA[(row0 + mt*16 + lan) * 72 + ks*32 + quad*8];
      #pragma unroll
      for (int nt = 0; nt < 4; ++nt)
        bvf[nt] = *(const bf16x8*)&sB[(col0 + nt*16 + lan) * 72 + ks*32 + quad*8];
      #pragma unroll
      for (int mt = 0; mt < 4; ++mt)
        #pragma unroll
        for (int nt = 0; nt < 4; ++nt)
          acc[mt][nt] = __builtin_amdgcn_mfma_f32_16x16x32_bf16(avf[mt], bvf[nt], acc[mt][nt], 0, 0, 0);
    }
    __syncthreads();
  }
  #pragma unroll
  for (int nt = 0; nt < 4; ++nt) {
    int c = col0 + nt * 16 + lan;
    float bias = (g == 0) ? b2[c] : 0.f;
    #pragma unroll
    for (int mt = 0; mt < 4; ++mt) {
      int rb = row0 + mt * 16 + quad * 4;
      #pragma unroll
      for (int i = 0; i < 4; ++i)
        out[(size_t)offs_tbl[rb + i] * CC + c] = acc[mt][nt][i] + bias;
    }
  }
}

extern "C" void kernel_launch(void* const* d_in, const int* in_sizes, int n_in,
                              void* d_out, int out_size, void* d_ws, size_t ws_size,
                              hipStream_t stream) {
  const float* x    = (const float*)d_in[0];
  const float* ln0w = (const float*)d_in[1];
  const float* ln0b = (const float*)d_in[2];
  const float* affw = (const float*)d_in[3];
  const float* w1   = (const float*)d_in[4];
  const float* b1   = (const float*)d_in[5];
  const float* gw   = (const float*)d_in[6];
  const float* gb   = (const float*)d_in[7];
  const float* w2   = (const float*)d_in[8];
  const float* b2   = (const float*)d_in[9];
  const float* tg   = (const float*)d_in[10];
  const float* fg   = (const float*)d_in[11];
  float* out = (float*)d_out;

  // h2 (bf16, 4096*49*256*2 = 102.8 MB) aliases d_out (f32, same byte count).
  // K2 writes row 0 (gate), K3 rows 1..48; K4 reads then overwrites in place.
  ushort* h2 = (ushort*)d_out;

  const size_t XN_BYTES = (size_t)NTOK * NSHC * CC * 2;   // 51.4 MB
  char* ws = (char*)d_ws;
  ushort* xn  = (ushort*)ws;
  ushort* h_t = (ushort*)(ws + XN_BYTES);                 // [n][o][56] bf16, 117.4 MB

  const int LDS_GEMM = 2 * 128 * 72 * 2 + 128 * 4;        // 37376 B

  k1_norm<<<NTOK, 256, 0, stream>>>(x, ln0w, ln0b, affw, xn, h_t);
  k2_h<<<dim3(1600, 2), 256, LDS_GEMM, stream>>>(xn, w1, b1, gw, gb, h_t, h2);
  k3_grid<<<NTOK / 4, 256, 0, stream>>>(h_t, tg, fg, h2);
  k4_out<<<1568, 256, LDS_GEMM, stream>>>(h2, w2, b2, out);
}

// Round 4
// 501.947 us; speedup vs baseline: 1.2962x; 1.2962x over previous
//
#include <hip/hip_runtime.h>
#include <stdint.h>

#define LMAXC 6
#define NSHC 49      // (LMAX+1)^2
#define CC 128
#define HH 256
#define NTOK 4096
#define NBA 182      // RB*RA = 14*13
#define EPSF 1e-5f

typedef __attribute__((ext_vector_type(8))) short bf16x8;
typedef __attribute__((ext_vector_type(4))) short s16x4;
typedef __attribute__((ext_vector_type(4))) float f32x4;

__device__ __forceinline__ float bf2f(ushort u) {
  union { uint32_t i; float f; } w; w.i = ((uint32_t)u) << 16; return w.f;
}
__device__ __forceinline__ ushort f2bf(float f) {
  union { float f; uint32_t i; } w; w.f = f;
  uint32_t u = w.i;
  return (ushort)((u + 0x7fffu + ((u >> 16) & 1u)) >> 16);
}
__device__ __forceinline__ bf16x8 pack8(float4 a, float4 b) {
  bf16x8 r;
  r[0] = (short)f2bf(a.x); r[1] = (short)f2bf(a.y);
  r[2] = (short)f2bf(a.z); r[3] = (short)f2bf(a.w);
  r[4] = (short)f2bf(b.x); r[5] = (short)f2bf(b.y);
  r[6] = (short)f2bf(b.z); r[7] = (short)f2bf(b.w);
  return r;
}
__device__ __forceinline__ float siluf(float v) { return v / (1.f + __expf(-v)); }

__device__ __forceinline__ float block_sum(float v, volatile float* red, int t) {
  #pragma unroll
  for (int off = 32; off > 0; off >>= 1) v += __shfl_down(v, off, 64);
  __syncthreads();
  if ((t & 63) == 0) red[t >> 6] = v;
  __syncthreads();
  return red[0] + red[1] + red[2] + red[3];
}

// ---------------- K1: normalization  x (f32) -> xn (bf16) ----------------
__global__ __launch_bounds__(256) void k1_norm(
    const float* __restrict__ x, const float* __restrict__ ln0w,
    const float* __restrict__ ln0b, const float* __restrict__ affw,
    ushort* __restrict__ xn)
{
  __shared__ float red[4];
  int n = blockIdx.x, t = threadIdx.x;
  const float4* xv = (const float4*)(x + (size_t)n * NSHC * CC);
  ushort* xnp = xn + (size_t)n * NSHC * CC;
  float4 vals[7];
  float s0 = 0.f, s0q = 0.f, fq = 0.f;
  #pragma unroll
  for (int p = 0; p < 7; ++p) {
    int idx = p * 256 + t;
    if (idx < 1568) {
      float4 v = xv[idx];
      vals[p] = v;
      int m = idx >> 5;
      if (m == 0) {
        s0  += v.x + v.y + v.z + v.w;
        s0q += v.x*v.x + v.y*v.y + v.z*v.z + v.w*v.w;
      } else {
        int l = (int)sqrtf((float)m + 0.5f);
        float bw = 1.f / ((float)(2*l+1) * 6.f);
        fq += bw * (v.x*v.x + v.y*v.y + v.z*v.z + v.w*v.w);
      }
    }
  }
  float S0 = block_sum(s0, red, t);
  float S0Q = block_sum(s0q, red, t);
  float FQ = block_sum(fq, red, t);
  float mu = S0 * (1.f / 128.f);
  float var = S0Q * (1.f / 128.f) - mu * mu;
  float rstd = rsqrtf(var + EPSF);
  float inv = rsqrtf(FQ * (1.f / 128.f) + EPSF);
  #pragma unroll
  for (int p = 0; p < 7; ++p) {
    int idx = p * 256 + t;
    if (idx < 1568) {
      int m = idx >> 5, c0 = (idx & 31) * 4;
      float4 v = vals[p];
      float o[4];
      if (m == 0) {
        o[0] = (v.x - mu) * rstd * ln0w[c0+0] + ln0b[c0+0];
        o[1] = (v.y - mu) * rstd * ln0w[c0+1] + ln0b[c0+1];
        o[2] = (v.z - mu) * rstd * ln0w[c0+2] + ln0b[c0+2];
        o[3] = (v.w - mu) * rstd * ln0w[c0+3] + ln0b[c0+3];
      } else {
        int l = (int)sqrtf((float)m + 0.5f);
        const float* aw = affw + (size_t)(l - 1) * CC;
        o[0] = v.x * inv * aw[c0+0];
        o[1] = v.y * inv * aw[c0+1];
        o[2] = v.z * inv * aw[c0+2];
        o[3] = v.w * inv * aw[c0+3];
      }
      s16x4 pk;
      #pragma unroll
      for (int j = 0; j < 4; ++j) pk[j] = (short)f2bf(o[j]);
      *(s16x4*)&xnp[idx * 4] = pk;
    }
  }
}

// ---------------- K2: grouped GEMM  h = xn @ W1_l^T (+b1) [n][m][o], gate -> h2 row0
// grid (1600, 2): x = row-blocks over 8 groups (7 l-groups + gate), y = 128-col chunk
__global__ __launch_bounds__(256) void k2_h(
    const ushort* __restrict__ xn, const float* __restrict__ w1,
    const float* __restrict__ b1, const float* __restrict__ gate_w,
    const float* __restrict__ gate_b, ushort* __restrict__ h,
    ushort* __restrict__ h2)
{
  extern __shared__ char smem[];
  ushort* sA = (ushort*)smem;              // 128 x 72
  ushort* sB = sA + 128 * 72;              // 128 x 72
  ushort* sE = (ushort*)smem;              // epilogue 128 x 136 u16 (34816 B, reuses sA/sB)
  int* offs_tbl = (int*)(sB + 128 * 72);   // at byte 36864
  const int cum[9] = {0, 32, 128, 288, 512, 800, 1152, 1568, 1600};
  int bx = blockIdx.x, colbase = blockIdx.y * 128, t = threadIdx.x;
  int g = 0;
  #pragma unroll
  for (int k = 1; k < 8; ++k) if (bx >= cum[k]) g = k;
  int nb = bx - cum[g];
  bool isGate = (g == 7);
  int l = isGate ? 0 : g;
  int d = isGate ? 1 : (2 * l + 1);
  int mbase = isGate ? 0 : l * l;
  const float* wB = isGate ? gate_w : (w1 + (size_t)l * HH * CC);

  if (t < 128) {
    int r = nb * 128 + t;
    int nn = r / d;
    offs_tbl[t] = nn * NSHC + mbase + (r - nn * d);
  }
  __syncthreads();

  int wave = t >> 6, lane = t & 63, quad = lane >> 4, lan = lane & 15;
  int row0 = (wave >> 1) * 64, col0 = (wave & 1) * 64;
  f32x4 acc[4][4];
  f32x4 zf = {0.f, 0.f, 0.f, 0.f};
  #pragma unroll
  for (int a = 0; a < 4; ++a)
    #pragma unroll
    for (int b = 0; b < 4; ++b) acc[a][b] = zf;

  const uint4* xv = (const uint4*)xn;
  const float4* wv = (const float4*)wB;
  for (int kc = 0; kc < 2; ++kc) {         // K = 128 in 2 chunks of 64
    #pragma unroll
    for (int p = 0; p < 4; ++p) {
      int idx = p * 256 + t, row = idx >> 3, c8 = idx & 7;
      *(uint4*)&sA[row * 72 + c8 * 8] = xv[(size_t)offs_tbl[row] * 16 + kc * 8 + c8];
    }
    #pragma unroll
    for (int p = 0; p < 4; ++p) {
      int idx = p * 256 + t, row = idx >> 3, c8 = idx & 7;
      size_t base = (size_t)(colbase + row) * 32 + kc * 16 + c8 * 2;
      *(bf16x8*)&sB[row * 72 + c8 * 8] = pack8(wv[base], wv[base + 1]);
    }
    __syncthreads();
    #pragma unroll
    for (int ks = 0; ks < 2; ++ks) {
      bf16x8 av[4], bv[4];
      #pragma unroll
      for (int mt = 0; mt < 4; ++mt)
        av[mt] = *(const bf16x8*)&sA[(row0 + mt*16 + lan) * 72 + ks*32 + quad*8];
      #pragma unroll
      for (int nt = 0; nt < 4; ++nt)
        bv[nt] = *(const bf16x8*)&sB[(col0 + nt*16 + lan) * 72 + ks*32 + quad*8];
      #pragma unroll
      for (int mt = 0; mt < 4; ++mt)
        #pragma unroll
        for (int nt = 0; nt < 4; ++nt)
          acc[mt][nt] = __builtin_amdgcn_mfma_f32_16x16x32_bf16(av[mt], bv[nt], acc[mt][nt], 0, 0, 0);
    }
    __syncthreads();
  }

  // epilogue: C tile -> LDS (pitch 136) -> coalesced b128 stores
  #pragma unroll
  for (int nt = 0; nt < 4; ++nt) {
    int c = col0 + nt * 16 + lan;
    int o = colbase + c;
    float bias = 0.f;
    if (g == 0) bias = b1[o];
    if (isGate) bias = gate_b[o];
    #pragma unroll
    for (int mt = 0; mt < 4; ++mt) {
      int rb = row0 + mt * 16 + quad * 4;
      #pragma unroll
      for (int i = 0; i < 4; ++i) {
        float v = acc[mt][nt][i] + bias;
        if (isGate) v = siluf(v);
        sE[(rb + i) * 136 + c] = f2bf(v);
      }
    }
  }
  __syncthreads();
  ushort* dst = isGate ? h2 : h;
  #pragma unroll
  for (int p = 0; p < 8; ++p) {
    int idx = p * 256 + t, r = idx >> 4, cc = idx & 15;
    bf16x8 vv = *(const bf16x8*)&sE[r * 136 + cc * 8];
    *(bf16x8*)&dst[(size_t)offs_tbl[r] * HH + colbase + cc * 8] = vv;
  }
}

// ---------------- K3: grid transform  ht = FG^T @ silu(TG @ h) -> h2 rows 1..48
// 4 tokens/block; conflict-free transpose staging (lane = o-row, b128 LDS writes)
__global__ __launch_bounds__(256, 2) void k3_grid(
    const ushort* __restrict__ h, const float* __restrict__ tg,
    const float* __restrict__ fg, ushort* __restrict__ h2)
{
  __shared__ ushort sH[256 * 72];    // h^T per token: [o][m], pitch 72, cols 49..63 zero
  __shared__ ushort sG[64 * 200];    // P per o-chunk: [o_loc][ba], pitch 200
  int t = threadIdx.x;
  int wave = t >> 6, lane = t & 63, quad = lane >> 4, lan = lane & 15;

  bf16x8 a1[3][2];                   // TG fragments: rows wave*48.., K=64 (2 ksteps)
  {
    for (int i = t; i < 192 * 72; i += 256) sH[i] = 0;
    __syncthreads();
    for (int i = t; i < NBA * NSHC; i += 256) {
      int ba = i / NSHC, m = i - ba * NSHC;
      sH[ba * 72 + m] = f2bf(tg[i]);
    }
    __syncthreads();
    #pragma unroll
    for (int mt = 0; mt < 3; ++mt)
      #pragma unroll
      for (int ks = 0; ks < 2; ++ks)
        a1[mt][ks] = *(const bf16x8*)&sH[(wave*48 + mt*16 + lan) * 72 + ks*32 + quad*8];
    __syncthreads();
  }
  bf16x8 a2[6];                      // FG^T fragments: rows wave*16.., K=192 (6 ksteps)
  {
    for (int i = t; i < 64 * 200; i += 256) sG[i] = 0;
    __syncthreads();
    for (int i = t; i < NBA * NSHC; i += 256) {
      int ba = i / NSHC, m = i - ba * NSHC;
      sG[m * 200 + ba] = f2bf(fg[i]);
    }
    __syncthreads();
    #pragma unroll
    for (int ks = 0; ks < 6; ++ks)
      a2[ks] = *(const bf16x8*)&sG[(wave*16 + lan) * 200 + ks*32 + quad*8];
    __syncthreads();
  }

  f32x4 zf = {0.f, 0.f, 0.f, 0.f};

  for (int it = 0; it < 4; ++it) {
    int tok = blockIdx.x * 4 + it;
    const ushort* hp = h + (size_t)tok * NSHC * HH;
    // transpose-stage: thread t owns o-row t; coalesced global u16 reads,
    // conflict-free ds_write_b128 row writes (pitch-72 start banks = 4*o mod 32)
    #pragma unroll
    for (int m0 = 0; m0 < 64; m0 += 8) {
      bf16x8 w;
      #pragma unroll
      for (int j = 0; j < 8; ++j) {
        int m = m0 + j;
        w[j] = (m < NSHC) ? (short)hp[(size_t)m * HH + t] : (short)0;
      }
      *(bf16x8*)&sH[t * 72 + m0] = w;
    }
    __syncthreads();

    for (int oc = 0; oc < 4; ++oc) {                   // H=256 in 4 chunks of 64
      f32x4 acc1[3][4];
      #pragma unroll
      for (int a = 0; a < 3; ++a)
        #pragma unroll
        for (int b = 0; b < 4; ++b) acc1[a][b] = zf;
      #pragma unroll
      for (int ks = 0; ks < 2; ++ks) {
        int kq = ks*32 + quad*8;
        bf16x8 bv[4];
        #pragma unroll
        for (int nt = 0; nt < 4; ++nt)
          bv[nt] = *(const bf16x8*)&sH[(oc*64 + nt*16 + lan) * 72 + kq];
        #pragma unroll
        for (int mt = 0; mt < 3; ++mt)
          #pragma unroll
          for (int nt = 0; nt < 4; ++nt)
            acc1[mt][nt] = __builtin_amdgcn_mfma_f32_16x16x32_bf16(a1[mt][ks], bv[nt], acc1[mt][nt], 0, 0, 0);
      }
      #pragma unroll
      for (int mt = 0; mt < 3; ++mt) {                 // silu -> sG[o_loc][ba]
        int ba0 = wave*48 + mt*16 + quad*4;
        #pragma unroll
        for (int nt = 0; nt < 4; ++nt) {
          int o_loc = nt*16 + lan;
          s16x4 pk;
          #pragma unroll
          for (int i = 0; i < 4; ++i) pk[i] = (short)f2bf(siluf(acc1[mt][nt][i]));
          *(s16x4*)&sG[o_loc * 200 + ba0] = pk;
        }
      }
      __syncthreads();
      f32x4 acc2[4];
      #pragma unroll
      for (int b = 0; b < 4; ++b) acc2[b] = zf;
      #pragma unroll
      for (int ks = 0; ks < 6; ++ks) {
        #pragma unroll
        for (int nt = 0; nt < 4; ++nt) {
          bf16x8 bv = *(const bf16x8*)&sG[(nt*16 + lan) * 200 + ks*32 + quad*8];
          acc2[nt] = __builtin_amdgcn_mfma_f32_16x16x32_bf16(a2[ks], bv, acc2[nt], 0, 0, 0);
        }
      }
      int mrow = wave * 16 + quad * 4;
      #pragma unroll
      for (int nt = 0; nt < 4; ++nt) {
        int o = oc * 64 + nt * 16 + lan;
        #pragma unroll
        for (int i = 0; i < 4; ++i) {
          int m = mrow + i;
          if (m >= 1 && m < NSHC)
            h2[((size_t)tok * NSHC + m) * HH + o] = f2bf(acc2[nt][i]);
        }
      }
      __syncthreads();
    }
  }
}

// ---------------- K4: grouped GEMM  out = h2 @ W2_l^T (+b2 on m=0), f32 out --
// NOTE: h2 aliases d_out (each block reads exactly the rows it overwrites; all
// reads complete in the K-loop before epilogue stores).
__global__ __launch_bounds__(256) void k4_out(
    const ushort* __restrict__ h2, const float* __restrict__ w2,
    const float* __restrict__ b2, float* __restrict__ out)
{
  extern __shared__ char smem[];
  ushort* sA = (ushort*)smem;              // 128 x 72
  ushort* sB = sA + 128 * 72;              // 128 x 72
  float* sE = (float*)smem;                // epilogue 64 x 132 f32 (33792 B)
  int* offs_tbl = (int*)(sB + 128 * 72);
  const int cum[8] = {0, 32, 128, 288, 512, 800, 1152, 1568};
  int bx = blockIdx.x, t = threadIdx.x;
  int g = 0;
  #pragma unroll
  for (int k = 1; k < 7; ++k) if (bx >= cum[k]) g = k;
  int nb = bx - cum[g];
  int l = g, d = 2*l+1, mbase = l*l;
  if (t < 128) {
    int r = nb * 128 + t;
    int nn = r / d;
    offs_tbl[t] = nn * NSHC + mbase + (r - nn * d);
  }
  __syncthreads();
  int wave = t >> 6, lane = t & 63, quad = lane >> 4, lan = lane & 15;
  int row0 = (wave >> 1) * 64, col0 = (wave & 1) * 64;
  f32x4 acc[4][4];
  f32x4 zf = {0.f, 0.f, 0.f, 0.f};
  #pragma unroll
  for (int a = 0; a < 4; ++a)
    #pragma unroll
    for (int b = 0; b < 4; ++b) acc[a][b] = zf;

  const uint4* av4 = (const uint4*)h2;
  const float4* wv = (const float4*)(w2 + (size_t)l * CC * HH);
  for (int kc = 0; kc < 4; ++kc) {         // K = 256 in 4 chunks of 64
    #pragma unroll
    for (int p = 0; p < 4; ++p) {
      int idx = p * 256 + t, row = idx >> 3, c8 = idx & 7;
      *(uint4*)&sA[row * 72 + c8 * 8] = av4[(size_t)offs_tbl[row] * 32 + kc * 8 + c8];
    }
    #pragma unroll
    for (int p = 0; p < 4; ++p) {
      int idx = p * 256 + t, row = idx >> 3, c8 = idx & 7;
      size_t base = (size_t)row * 64 + kc * 16 + c8 * 2;
      *(bf16x8*)&sB[row * 72 + c8 * 8] = pack8(wv[base], wv[base + 1]);
    }
    __syncthreads();
    #pragma unroll
    for (int ks = 0; ks < 2; ++ks) {
      bf16x8 avf[4], bvf[4];
      #pragma unroll
      for (int mt = 0; mt < 4; ++mt)
        avf[mt] = *(const bf16x8*)&sA[(row0 + mt*16 + lan) * 72 + ks*32 + quad*8];
      #pragma unroll
      for (int nt = 0; nt < 4; ++nt)
        bvf[nt] = *(const bf16x8*)&sB[(col0 + nt*16 + lan) * 72 + ks*32 + quad*8];
      #pragma unroll
      for (int mt = 0; mt < 4; ++mt)
        #pragma unroll
        for (int nt = 0; nt < 4; ++nt)
          acc[mt][nt] = __builtin_amdgcn_mfma_f32_16x16x32_bf16(avf[mt], bvf[nt], acc[mt][nt], 0, 0, 0);
    }
    __syncthreads();
  }

  // epilogue: two 64-row halves through LDS (pitch 132 f32) -> float4 stores
  #pragma unroll
  for (int half = 0; half < 2; ++half) {
    if ((wave >> 1) == half) {
      #pragma unroll
      for (int nt = 0; nt < 4; ++nt) {
        int c = col0 + nt * 16 + lan;
        float bias = (g == 0) ? b2[c] : 0.f;
        #pragma unroll
        for (int mt = 0; mt < 4; ++mt) {
          int rr = mt * 16 + quad * 4;
          #pragma unroll
          for (int i = 0; i < 4; ++i)
            sE[(rr + i) * 132 + c] = acc[mt][nt][i] + bias;
        }
      }
    }
    __syncthreads();
    #pragma unroll
    for (int p = 0; p < 8; ++p) {
      int idx = p * 256 + t, r = idx >> 5, cc = idx & 31;
      float4 v = *(const float4*)&sE[r * 132 + cc * 4];
      *(float4*)&out[(size_t)offs_tbl[half * 64 + r] * CC + cc * 4] = v;
    }
    __syncthreads();
  }
}

extern "C" void kernel_launch(void* const* d_in, const int* in_sizes, int n_in,
                              void* d_out, int out_size, void* d_ws, size_t ws_size,
                              hipStream_t stream) {
  const float* x    = (const float*)d_in[0];
  const float* ln0w = (const float*)d_in[1];
  const float* ln0b = (const float*)d_in[2];
  const float* affw = (const float*)d_in[3];
  const float* w1   = (const float*)d_in[4];
  const float* b1   = (const float*)d_in[5];
  const float* gw   = (const float*)d_in[6];
  const float* gb   = (const float*)d_in[7];
  const float* w2   = (const float*)d_in[8];
  const float* b2   = (const float*)d_in[9];
  const float* tg   = (const float*)d_in[10];
  const float* fg   = (const float*)d_in[11];
  float* out = (float*)d_out;

  // h2 (bf16, 4096*49*256*2 = 102.8 MB) aliases d_out (f32, same byte count).
  // K2 writes row 0 (gate), K3 rows 1..48; K4 reads then overwrites in place.
  ushort* h2 = (ushort*)d_out;

  const size_t XN_BYTES = (size_t)NTOK * NSHC * CC * 2;   // 51.4 MB
  char* ws = (char*)d_ws;
  ushort* xn = (ushort*)ws;
  ushort* h  = (ushort*)(ws + XN_BYTES);                  // [n][m][o] bf16, 102.8 MB

  const int LDS_GEMM = 2 * 128 * 72 * 2 + 128 * 4;        // 37376 B

  k1_norm<<<NTOK, 256, 0, stream>>>(x, ln0w, ln0b, affw, xn);
  k2_h<<<dim3(1600, 2), 256, LDS_GEMM, stream>>>(xn, w1, b1, gw, gb, h, h2);
  k3_grid<<<NTOK / 4, 256, 0, stream>>>(h, tg, fg, h2);
  k4_out<<<1568, 256, LDS_GEMM, stream>>>(h2, w2, b2, out);
}